// Round 5
// baseline (676.654 us; speedup 1.0000x reference)
//
#include <hip/hip_runtime.h>

// TTFS encoder: out[b][t][n] = 1.0f at the first t where the leaky-integrate
// membrane crosses V_TH=1.0, else 0.0f. One-hot (or zero) per (b,n) column.
//
// ===== R8: DIAGNOSTIC ROUND (intentionally slower; best kernel = R4) =====
// Five rounds of store-side interventions all returned NULL deltas:
//   R2->R3 nt vs plain: 0.0 | R4 decoupled vs interleaved: 0.0
//   R6 pure-fill kernel: regression consistent w/ same store rate
//   R7 25% vs 100% occupancy: 0.0
// Two consistent worlds remain:
//   A) our kernel ~177us, stores gated ~3 TB/s by something invisible to all
//      counters and invariant to every knob we turned;
//   B) our kernel ~90-100us (write roofline); the 522us window = 345us arena
//      poison fill + ~80us of tiny reset dispatches + our kernel.
// We have NEVER seen our kernel's own rocprof row (the ~340us fill rows own
// the top-5 cutoff). This round makes it visible: run the dense one-hot
// store sweep 4x (2 GiB total writes) so our kernel exceeds 340us and lands
// in the top-5 with its own WRITE_SIZE / hbm_gbps / FETCH_SIZE.
// Passes are separated by asm volatile memory clobbers so DSE cannot remove
// passes 1-3; pass 4 writes the correct values -> absmax stays 0.0.
// Decision rule (pre-committed):
//   kernel row ~360-400us @ ~5.5-6 TB/s, dur ~780-820  => World B: revert to
//     R4 next round and declare ROOFLINE with direct evidence.
//   kernel row ~650-720us @ ~3 TB/s, dur ~1050         => World A: store-path
//     gap is real; FETCH_SIZE tells us if it's RFO over-fetch; chase resumes.
//
// Bit-exactness notes (output is {0,1}: one flipped element = absmax 1.0):
//  - decay = fp32(exp(-0.5)) correctly rounded; (1-decay) exact (Sterbenz).
//  - mem update is mul-then-add round-to-nearest, NOT fma (__fmul_rn/__fadd_rn
//    block -ffp-contract=fast).
//  - drive = (x*s)*(1-decay) precomputed once: deterministic, same rounding
//    as reference's per-step current*(1-decay).

#define T_STEPS 64
#define N_COLS  1024

typedef float vfloat4 __attribute__((ext_vector_type(4)));

__global__ __launch_bounds__(256) void ttfs_encode_kernel(
    const float* __restrict__ x,
    const float* __restrict__ sens,
    float* __restrict__ out)
{
    const int b   = blockIdx.x;
    const int tid = threadIdx.x;      // 0..255, each owns 4 consecutive cols
    const int n0  = tid * 4;

    const float decay = 0.60653065971263342f;  // fp32(exp(-0.5)), CR
    const float omd   = 1.0f - decay;          // exact (Sterbenz)

    const vfloat4 xv = *reinterpret_cast<const vfloat4*>(x + (size_t)b * N_COLS + n0);
    const vfloat4 sv = *reinterpret_cast<const vfloat4*>(sens + n0);

    // drive_i = (x*s)*(1-decay): two rn muls, matching reference op order.
    float drive[4];
    #pragma unroll
    for (int i = 0; i < 4; ++i)
        drive[i] = __fmul_rn(__fmul_rn(xv[i], sv[i]), omd);

    // Phase 1: exact recurrence in registers; record first-spike step.
    int   tstar[4] = {T_STEPS, T_STEPS, T_STEPS, T_STEPS};  // T_STEPS = never
    float mem[4]   = {0.f, 0.f, 0.f, 0.f};

    #pragma unroll 8
    for (int t = 0; t < T_STEPS; ++t) {
        #pragma unroll
        for (int i = 0; i < 4; ++i) {
            float m = __fadd_rn(__fmul_rn(mem[i], decay), drive[i]);
            const bool spike = (m >= 1.0f);
            if (spike && tstar[i] == T_STEPS) tstar[i] = t;  // first spike only
            mem[i] = spike ? 0.0f : m;
        }
    }

    // Phase 2 (DIAGNOSTIC): dense one-hot store sweep, repeated 4x to make
    // this kernel's HBM-write row visible in rocprof top-5. Memory clobber
    // between passes prevents dead-store elimination of passes 1-3. The
    // final pass writes the correct one-hot values.
    #pragma unroll 1
    for (int rep = 0; rep < 4; ++rep) {
        float* outp = out + (size_t)b * T_STEPS * N_COLS + n0;
        #pragma unroll 8
        for (int t = 0; t < T_STEPS; ++t) {
            vfloat4 ov;
            #pragma unroll
            for (int i = 0; i < 4; ++i)
                ov[i] = (t == tstar[i]) ? 1.0f : 0.0f;
            *reinterpret_cast<vfloat4*>(outp) = ov;
            outp += N_COLS;
        }
        asm volatile("" ::: "memory");  // keep all passes' stores live
    }
}

extern "C" void kernel_launch(void* const* d_in, const int* in_sizes, int n_in,
                              void* d_out, int out_size, void* d_ws, size_t ws_size,
                              hipStream_t stream) {
    const float* x    = (const float*)d_in[0];   // [B, N] fp32
    const float* sens = (const float*)d_in[1];   // [N]    fp32
    float*       out  = (float*)d_out;           // [B, T, N] fp32

    const int N = in_sizes[1];                   // 1024
    const int B = in_sizes[0] / N;               // 2048
    (void)N; (void)out_size; (void)d_ws; (void)ws_size; (void)n_in;

    ttfs_encode_kernel<<<dim3(B), dim3(256), 0, stream>>>(x, sens, out);
}

// Round 6
// 521.487 us; speedup vs baseline: 1.2975x; 1.2975x over previous
//
#include <hip/hip_runtime.h>

// TTFS encoder: out[b][t][n] = 1.0f at the first t where the leaky-integrate
// membrane crosses V_TH=1.0, else 0.0f. One-hot (or zero) per (b,n) column.
//
// ===== R9: REVERT TO SESSION-BEST (R4) — roofline case closed =====
// R8 diagnostic (4x dense store passes): dur 522->677, i.e. +154us for 3
// extra 512-MiB passes = ~10.5 TB/s effective => extra passes were combined
// in L2/MALL before HBM (per-block 256 KiB rewritten within ~1us). Therefore:
//  (1) our store path up to L2 retires >=10 TB/s — no gate there;
//  (2) L2->HBM writeback is line-granular and kernel-agnostic, and the rocclr
//      arena fill proves that path sustains 6.24 TB/s for full-line dirty
//      data; our stores are full-line like the fill's. No gate possible there.
// => This kernel runs at ~512MiB / 6.2TB/s ~= 90us, ~95% of the achieved
//    write roofline. The 522us bench window = ~345us harness arena-poison
//    fill (WRITE_SIZE=2GiB, 4x our output) + ~85us of tiny reset dispatches
//    and launch gaps + this kernel. Not addressable from kernel_launch.
// Null-result ledger (all single-variable): nt vs plain stores (0.0),
// store/compute decoupling (0.0), 25% vs 100% occupancy (0.0), split
// fill+scatter (+61us: redundant traffic + extra launch).
//
// Bit-exactness notes (output is {0,1}: one flipped element = absmax 1.0):
//  - decay = fp32(exp(-0.5)) correctly rounded; (1-decay) exact (Sterbenz).
//  - mem update is mul-then-add round-to-nearest, NOT fma (__fmul_rn/__fadd_rn
//    block -ffp-contract=fast).
//  - drive = (x*s)*(1-decay) precomputed once: deterministic, same rounding
//    as reference's per-step current*(1-decay).

#define T_STEPS 64
#define N_COLS  1024

typedef float vfloat4 __attribute__((ext_vector_type(4)));

__global__ __launch_bounds__(256) void ttfs_encode_kernel(
    const float* __restrict__ x,
    const float* __restrict__ sens,
    float* __restrict__ out)
{
    const int b   = blockIdx.x;
    const int tid = threadIdx.x;      // 0..255, each owns 4 consecutive cols
    const int n0  = tid * 4;

    const float decay = 0.60653065971263342f;  // fp32(exp(-0.5)), CR
    const float omd   = 1.0f - decay;          // exact (Sterbenz)

    const vfloat4 xv = *reinterpret_cast<const vfloat4*>(x + (size_t)b * N_COLS + n0);
    const vfloat4 sv = *reinterpret_cast<const vfloat4*>(sens + n0);

    // drive_i = (x*s)*(1-decay): two rn muls, matching reference op order.
    float drive[4];
    #pragma unroll
    for (int i = 0; i < 4; ++i)
        drive[i] = __fmul_rn(__fmul_rn(xv[i], sv[i]), omd);

    // Phase 1: exact recurrence in registers; record first-spike step.
    int   tstar[4] = {T_STEPS, T_STEPS, T_STEPS, T_STEPS};  // T_STEPS = never
    float mem[4]   = {0.f, 0.f, 0.f, 0.f};

    #pragma unroll 8
    for (int t = 0; t < T_STEPS; ++t) {
        #pragma unroll
        for (int i = 0; i < 4; ++i) {
            float m = __fadd_rn(__fmul_rn(mem[i], decay), drive[i]);
            const bool spike = (m >= 1.0f);
            if (spike && tstar[i] == T_STEPS) tstar[i] = t;  // first spike only
            mem[i] = spike ? 0.0f : m;
        }
    }

    // Phase 2: dense one-hot store sweep — write-once, full-line coalesced
    // 1 KiB/wave. Runs at ~95% of the achieved write roofline.
    float* outp = out + (size_t)b * T_STEPS * N_COLS + n0;
    #pragma unroll 8
    for (int t = 0; t < T_STEPS; ++t) {
        vfloat4 ov;
        #pragma unroll
        for (int i = 0; i < 4; ++i)
            ov[i] = (t == tstar[i]) ? 1.0f : 0.0f;
        *reinterpret_cast<vfloat4*>(outp) = ov;
        outp += N_COLS;
    }
}

extern "C" void kernel_launch(void* const* d_in, const int* in_sizes, int n_in,
                              void* d_out, int out_size, void* d_ws, size_t ws_size,
                              hipStream_t stream) {
    const float* x    = (const float*)d_in[0];   // [B, N] fp32
    const float* sens = (const float*)d_in[1];   // [N]    fp32
    float*       out  = (float*)d_out;           // [B, T, N] fp32

    const int N = in_sizes[1];                   // 1024
    const int B = in_sizes[0] / N;               // 2048
    (void)N; (void)out_size; (void)d_ws; (void)ws_size; (void)n_in;

    ttfs_encode_kernel<<<dim3(B), dim3(256), 0, stream>>>(x, sens, out);
}